// Round 1
// baseline (35.937 us; speedup 1.0000x reference)
//
#include <hip/hip_runtime.h>

#define H_IMG   500
#define W_IMG   512
#define KPP     10
#define N_PTS   8192
#define TILE    16
#define TX_TILES 32              // 512/16
#define TY_TILES 32              // ceil(500/16) -> covers rows 0..511, rows >=500 masked
#define N_TILES (TX_TILES * TY_TILES)
#define CAP     256              // max points per tile list (center density ~40, Poisson tail << CAP)
#define IMG_ELEMS (H_IMG * W_IMG * 3)   // 768000

// ---------------------------------------------------------------------------
// Kernel 1: project points to NDC, bin into 16x16-pixel tiles (conservative
// bbox of the radius-R disk, +/-1 px slack).
// ---------------------------------------------------------------------------
__global__ void pcd_bin_kernel(const float* __restrict__ pts,
                               float4* __restrict__ proj,
                               int* __restrict__ cnts,
                               int* __restrict__ lists) {
#pragma clang fp contract(off)
    int i = blockIdx.x * 256 + threadIdx.x;
    if (i >= N_PTS) return;

    float x = pts[i * 3 + 0];
    float y = pts[i * 3 + 1];
    float z = pts[i * 3 + 2];

    // Exact replication of reference f32 op order:
    //   u = -FX*x/z + PX ; x_ndc = -(2u - W)/S_MIN
    float u  = -575.0f * x / z + 256.0f;
    float v  = -575.0f * y / z + 250.0f;
    float xn = -(2.0f * u - 512.0f) / 500.0f;
    float yn = -(2.0f * v - 500.0f) / 500.0f;

    proj[i] = make_float4(xn, yn, z, __int_as_float(i));

    if (!(z > 0.0f)) return;   // reference: valid requires z > 0

    const float R = 0.005f;
    // pixel w satisfies |xs[w]-xn|<R  with xs[w] = (W-1-2w)/S_MIN
    float wlo_f = (511.0f - 500.0f * (xn + R)) * 0.5f - 1.0f;
    float whi_f = (511.0f - 500.0f * (xn - R)) * 0.5f + 1.0f;
    float hlo_f = (499.0f - 500.0f * (yn + R)) * 0.5f - 1.0f;
    float hhi_f = (499.0f - 500.0f * (yn - R)) * 0.5f + 1.0f;

    // guard int conversion range
    wlo_f = fmaxf(fminf(wlo_f, 1.0e6f), -1.0e6f);
    whi_f = fmaxf(fminf(whi_f, 1.0e6f), -1.0e6f);
    hlo_f = fmaxf(fminf(hlo_f, 1.0e6f), -1.0e6f);
    hhi_f = fmaxf(fminf(hhi_f, 1.0e6f), -1.0e6f);

    int wlo = max(0, (int)floorf(wlo_f));
    int whi = min(W_IMG - 1, (int)ceilf(whi_f));
    int hlo = max(0, (int)floorf(hlo_f));
    int hhi = min(H_IMG - 1, (int)ceilf(hhi_f));
    if (wlo > whi || hlo > hhi) return;

    int tx0 = wlo >> 4, tx1 = whi >> 4;
    int ty0 = hlo >> 4, ty1 = hhi >> 4;
    for (int ty = ty0; ty <= ty1; ++ty) {
        for (int tx = tx0; tx <= tx1; ++tx) {
            int t = ty * TX_TILES + tx;
            int pos = atomicAdd(&cnts[t], 1);
            if (pos < CAP) lists[t * CAP + pos] = i;
        }
    }
}

// ---------------------------------------------------------------------------
// Kernel 2: render one 16x16 tile per block, one pixel per thread.
// Top-KPP-by-(z, idx) kept sorted in registers (fully unrolled -> no scratch).
// ---------------------------------------------------------------------------
__global__ void pcd_render_kernel(const float4* __restrict__ proj,
                                  const int* __restrict__ cnts,
                                  const int* __restrict__ lists,
                                  const float* __restrict__ feats,
                                  float* __restrict__ out) {
#pragma clang fp contract(off)
    __shared__ float4 sp[CAP];

    int tile = blockIdx.x;
    int n = cnts[tile];
    n = n < CAP ? n : CAP;

    for (int j = threadIdx.x; j < n; j += 256) {
        sp[j] = proj[lists[tile * CAP + j]];
    }
    __syncthreads();

    int tx = threadIdx.x & 15;
    int ty = threadIdx.x >> 4;
    int w = (tile % TX_TILES) * TILE + tx;
    int h = (tile / TX_TILES) * TILE + ty;

    // xs_pix = -(2*(w+0.5) - W)/S_MIN ; exact until the /500
    float xs = -(2.0f * ((float)w + 0.5f) - 512.0f) / 500.0f;
    float ys = -(2.0f * ((float)h + 0.5f) - 500.0f) / 500.0f;

    const float R2 = 0.005f * 0.005f;

    float zk[KPP];
    float dk[KPP];
    int   ik[KPP];
#pragma unroll
    for (int k = 0; k < KPP; ++k) { zk[k] = __builtin_inff(); dk[k] = 0.0f; ik[k] = 0x7fffffff; }

    for (int j = 0; j < n; ++j) {
        float4 p = sp[j];                 // same addr across wave -> LDS broadcast
        float dx = xs - p.x;
        float dy = ys - p.y;
        float dx2 = dx * dx;              // contract(off): separate roundings like numpy
        float dy2 = dy * dy;
        float d2 = dx2 + dy2;
        if (d2 < R2) {
            float cz = p.z, cd = d2;
            int ci = __float_as_int(p.w);
            // sorted bubble-insert: ascending (z, idx); static indices only
#pragma unroll
            for (int k = 0; k < KPP; ++k) {
                bool lt = (cz < zk[k]) || (cz == zk[k] && ci < ik[k]);
                float tz = zk[k], td = dk[k];
                int ti = ik[k];
                if (lt) {
                    zk[k] = cz; dk[k] = cd; ik[k] = ci;
                    cz = tz; cd = td; ci = ti;
                }
            }
        }
    }

    if (h < H_IMG) {
        float T = 1.0f;
        float c0 = 0.0f, c1 = 0.0f, c2 = 0.0f;
        int base = h * W_IMG + w;
        float* zout = out + IMG_ELEMS + base * KPP;
#pragma unroll
        for (int k = 0; k < KPP; ++k) {
            bool ok = zk[k] < __builtin_inff();
            float wt = ok ? (1.0f - dk[k] / R2) : 0.0f;
            float a = wt * T;               // wts[k] * prev[k]  (prev = running cumprod)
            if (ok) {
                int fi = ik[k] * 3;
                c0 += a * feats[fi + 0];
                c1 += a * feats[fi + 1];
                c2 += a * feats[fi + 2];
            }
            T = T * (1.0f - wt);
            zout[k] = ok ? zk[k] : -1.0f;
        }
        out[base * 3 + 0] = c0;
        out[base * 3 + 1] = c1;
        out[base * 3 + 2] = c2;
    }
}

// ---------------------------------------------------------------------------
extern "C" void kernel_launch(void* const* d_in, const int* in_sizes, int n_in,
                              void* d_out, int out_size, void* d_ws, size_t ws_size,
                              hipStream_t stream) {
    const float* points = (const float*)d_in[0];   // (8192, 3) f32
    const float* feats  = (const float*)d_in[1];   // (8192, 3) f32
    float* out = (float*)d_out;                    // 768000 img + 2560000 zbuf f32

    // workspace layout
    float4* proj = (float4*)d_ws;                               // 8192 * 16 B
    int* cnts = (int*)((char*)d_ws + N_PTS * sizeof(float4));   // 1024 * 4 B
    int* lists = cnts + N_TILES;                                // 1024 * CAP * 4 B

    hipMemsetAsync(cnts, 0, N_TILES * sizeof(int), stream);

    pcd_bin_kernel<<<(N_PTS + 255) / 256, 256, 0, stream>>>(points, proj, cnts, lists);
    pcd_render_kernel<<<N_TILES, 256, 0, stream>>>(proj, cnts, lists, feats, out);
}